// Round 8
// baseline (147.782 us; speedup 1.0000x reference)
//
#include <hip/hip_runtime.h>

typedef __attribute__((ext_vector_type(8))) short bf16x8;
typedef __attribute__((ext_vector_type(4))) float f32x4;
typedef __attribute__((ext_vector_type(4))) unsigned short us4;

#define E_DIM 100
#define L_SEQ 20
#define NV    30000
#define NVP   30080
#define MROWS 2000
#define KP    128
#define KW    112       // whh padded K
#define RSESS 16

__device__ inline unsigned short f2bf(float f){
  unsigned int u = __float_as_uint(f);
  return (unsigned short)((u + 0x7fffu + ((u>>16)&1u)) >> 16);
}
__device__ inline float dot4(float4 a, float4 b){
  return a.x*b.x + a.y*b.y + a.z*b.z + a.w*b.w;
}
__device__ inline void store4bf(unsigned short* dst, float4 x){
  us4 p = { f2bf(x.x), f2bf(x.y), f2bf(x.z), f2bf(x.w) };
  *(us4*)dst = p;
}
// fast sigmoid/tanh via v_exp_f32 (1-instr exp2); tanh clamped to avoid inf-inf
__device__ inline float fsig(float x){
  float t = __builtin_amdgcn_exp2f(x * -1.44269504f);
  return __builtin_amdgcn_rcpf(1.f + t);
}
__device__ inline float ftanh(float x){
  float cx = fminf(fmaxf(x, -15.f), 15.f);
  float t = __builtin_amdgcn_exp2f(cx * 2.88539008f);
  return (t - 1.f) * __builtin_amdgcn_rcpf(t + 1.f);
}

// ---------------- G: build all bf16 operands (pure streaming) ----------------
#define C1     962560
#define C2    1044480
#define C3    1060864
#define C4    1072064
#define C5    1072576
__global__ void gather_kernel(const int* __restrict__ seq, const int* __restrict__ ss2,
    const float* __restrict__ item, const float* __restrict__ W_ih,
    const float* __restrict__ W_hh, const float* __restrict__ b_ih,
    const float* __restrict__ b_hh,
    unsigned short* __restrict__ ib, unsigned short* __restrict__ xg,
    unsigned short* __restrict__ wihb, unsigned short* __restrict__ whhb,
    float* __restrict__ biasv){
  int id = blockIdx.x*256 + threadIdx.x;
  if (id < C1){
    int v = id >> 5, k4 = (id & 31) << 2;
    float4 x = {0.f,0.f,0.f,0.f};
    if (v < NV && k4 < 100) x = *(const float4*)(item + (size_t)v*E_DIM + k4);
    store4bf(ib + (size_t)v*KP + k4, x);
  } else if (id < C2){
    int idx = id - C1;
    int m = idx >> 5, k4 = (idx & 31) << 2;
    int src = -1;
    if (m < MROWS) src = seq[m];
    else if (m >= 2048 && m < 2548) src = ss2[(m-2048)*L_SEQ];
    float4 x = {0.f,0.f,0.f,0.f};
    if (src >= 0 && k4 < 100) x = *(const float4*)(item + (size_t)src*E_DIM + k4);
    store4bf(xg + (size_t)m*KP + k4, x);
  } else if (id < C3){
    int idx = id - C2;
    int j = idx >> 5, k4 = (idx & 31) << 2;
    float4 x = {0.f,0.f,0.f,0.f};
    if (j < 400 && k4 < 100) x = *(const float4*)(W_ih + (size_t)j*E_DIM + k4);
    store4bf(wihb + (size_t)j*KP + k4, x);
  } else if (id < C4){
    int idx = id - C3;
    int j = idx / 28, k4 = (idx - j*28) << 2;
    float4 x = {0.f,0.f,0.f,0.f};
    if (k4 < 100) x = *(const float4*)(W_hh + (size_t)j*E_DIM + k4);
    store4bf(whhb + (size_t)j*KW + k4, x);
  } else if (id < C5){
    int n = id - C4;
    biasv[n] = (n < 400) ? (b_ih[n] + b_hh[n]) : 0.f;
  }
}

// ---------------- GX: gx[m][n] = xg[m] . wihb[n] + biasv[n] (MFMA) ----------------
__global__ __launch_bounds__(256) void gxgemm_kernel(
    const unsigned short* __restrict__ xg, const unsigned short* __restrict__ wihb,
    const float* __restrict__ biasv, float* __restrict__ gx){
  __shared__ unsigned short As[128*KP];
  __shared__ unsigned short Bs[128*KP];
  int tile_m = blockIdx.x >> 2;
  int tile_n = blockIdx.x & 3;
  int tid = threadIdx.x;
  const float4* Ag = (const float4*)(xg   + (size_t)tile_m*128*KP);
  const float4* Bg = (const float4*)(wihb + (size_t)tile_n*128*KP);
  float4* As4=(float4*)As; float4* Bs4=(float4*)Bs;
#pragma unroll
  for (int i=0;i<8;i++){
    int chunk = i*256 + tid;
    int row = chunk >> 4;
    int cb  = (chunk & 15) << 4;
    int sw  = cb ^ ((row & 7) << 4);
    int di  = row*16 + (sw >> 4);
    As4[di] = Ag[chunk];
    Bs4[di] = Bg[chunk];
  }
  __syncthreads();
  int wave = tid >> 6, lane = tid & 63;
  int wm = (wave >> 1) << 6, wn = (wave & 1) << 6;
  int lrow = lane & 15, lq = lane >> 4;
  f32x4 acc[4][4];
#pragma unroll
  for (int i=0;i<4;i++)
#pragma unroll
    for (int jj=0;jj<4;jj++) acc[i][jj] = (f32x4){0.f,0.f,0.f,0.f};
#pragma unroll
  for (int kk=0;kk<4;kk++){
    int koffb = (kk*32 + lq*8) * 2;
    bf16x8 a[4], bfr[4];
#pragma unroll
    for (int i=0;i<4;i++){
      int row = wm + i*16 + lrow;
      int boff = koffb ^ ((row & 7) << 4);
      a[i] = *(const bf16x8*)(As + row*KP + (boff >> 1));
    }
#pragma unroll
    for (int jj=0;jj<4;jj++){
      int row = wn + jj*16 + lrow;
      int boff = koffb ^ ((row & 7) << 4);
      bfr[jj] = *(const bf16x8*)(Bs + row*KP + (boff >> 1));
    }
#pragma unroll
    for (int i=0;i<4;i++)
#pragma unroll
      for (int jj=0;jj<4;jj++)
        acc[i][jj] = __builtin_amdgcn_mfma_f32_16x16x32_bf16(bfr[jj], a[i], acc[i][jj], 0, 0, 0);
  }
  int n0 = tile_n*128 + wn + lq*4;
  int m0 = tile_m*128 + wm + lrow;
#pragma unroll
  for (int i=0;i<4;i++){
    int m = m0 + i*16;
#pragma unroll
    for (int jj=0;jj<4;jj++){
      int n = n0 + jj*16;
      if (n < 400){
        float4 bv = *(const float4*)(biasv + n);
        *(float4*)(gx + (size_t)m*400 + n) =
          (float4){acc[i][jj][0]+bv.x, acc[i][jj][1]+bv.y, acc[i][jj][2]+bv.z, acc[i][jj][3]+bv.w};
      }
    }
  }
}

// ---------------- REC: batched LSTM recurrence, 16 sessions/block, MFMA ----------------
// gates[16 x 400] = h[16 x K] @ W_hh^T[K x 400] per step; W_hh frags pinned in
// VGPRs (~96 in arrays, no spill), h state bf16 in XOR-swizzled LDS.
__global__ __launch_bounds__(512,1) void rec_kernel(
    const unsigned short* __restrict__ whhb, const float* __restrict__ gx,
    float* __restrict__ hu){
  int sess0 = blockIdx.x * RSESS;
  int tid = threadIdx.x;
  int wave = tid >> 6, lane = tid & 63;
  int lrow = lane & 15, lq = lane >> 4;
  __shared__ unsigned char hsbb[RSESS*256];   // bf16 h[16][128], XOR-swizzled
  __shared__ float gsh[RSESS][404];           // padded row -> 2-way LDS writes
  for (int u = tid; u < RSESS*128; u += 512) ((unsigned short*)hsbb)[u] = 0;

  // X-frags: wave owns n-tiles {wave, wave+8, wave+16, wave+24}
  bf16x8 xf[4][4];
  bool ntv[4]; int ntl[4];
#pragma unroll
  for (int i=0;i<4;i++){
    int nt = wave + 8*i;
    ntv[i] = (nt < 25); ntl[i] = nt;
#pragma unroll
    for (int ks=0; ks<4; ks++){
      bf16x8 z = {0,0,0,0,0,0,0,0};
      int k = ks*32 + lq*8;
      if (ntv[i] && k < KW)
        z = *(const bf16x8*)(whhb + (size_t)(nt*16 + lrow)*KW + k);
      xf[i][ks] = z;
    }
  }
  float cst[4] = {0.f,0.f,0.f,0.f};
  __syncthreads();

  for (int tt=0; tt<L_SEQ; tt++){
    // Y-frags: h rows (swizzled read, 16B aligned)
    bf16x8 yf[4];
#pragma unroll
    for (int ks=0; ks<4; ks++){
      int byte = (lrow*256 + (ks*32 + lq*8)*2) ^ ((lrow & 7) << 4);
      yf[ks] = *(const bf16x8*)(hsbb + byte);
    }
#pragma unroll
    for (int i=0;i<4;i++){
      if (ntv[i]){
        f32x4 acc = (f32x4){0.f,0.f,0.f,0.f};
#pragma unroll
        for (int ks=0; ks<4; ks++)
          acc = __builtin_amdgcn_mfma_f32_16x16x32_bf16(xf[i][ks], yf[ks], acc, 0, 0, 0);
        // C/D: col(lane&15)=session, row-axis=(lane>>4)*4+r = gate-n
        *(f32x4*)(&gsh[lrow][ntl[i]*16 + lq*4]) = acc;
      }
    }
    __syncthreads();
    // nonlinearity: 1600 cells over 512 threads (static c-state index)
#pragma unroll
    for (int r=0; r<4; r++){
      int u = tid + 512*r;
      if (u < 1600){
        int s = u / 100, j = u - s*100;
        size_t m = (size_t)(sess0 + s)*L_SEQ + tt;
        const float* gr = gx + m*400;
        float g0 = gsh[s][j      ] + gr[j      ];
        float g1 = gsh[s][j + 100] + gr[j + 100];
        float g2 = gsh[s][j + 200] + gr[j + 200];
        float g3 = gsh[s][j + 300] + gr[j + 300];
        float ig = fsig(g0), fg = fsig(g1);
        float gg = ftanh(g2), og = fsig(g3);
        cst[r] = fg*cst[r] + ig*gg;
        float h = og * ftanh(cst[r]);
        *(unsigned short*)(hsbb + ((s*256 + j*2) ^ ((s & 7) << 4))) = f2bf(h);
        if (sess0 + s < 100) hu[m*100 + j] = h;
      }
    }
    __syncthreads();
  }
}

// ---------------- REST: stageb + GAT + sr per session (from verified R7 prep) --------
__global__ __launch_bounds__(512,1) void rest_kernel(
    const int* __restrict__ sn2, const int* __restrict__ mask,
    const float* __restrict__ user, const float* __restrict__ W1,
    const float* __restrict__ W2, const float* __restrict__ Wg0,
    const float* __restrict__ gx, const float* __restrict__ hu,
    unsigned short* __restrict__ srb){
  int b = blockIdx.x, tid = threadIdx.x;
  __shared__ float4 hu4[L_SEQ][25];
  __shared__ float4 stcat4[5][50];
  __shared__ float  ls2l[5][100];
  __shared__ float  ns[6][100];
  __shared__ float  wsc[8];
  __shared__ float  ctx[100];
  __shared__ float4 h04[25];

  // load this session's hu rows (contiguous 2000 floats)
  for (int u = tid; u < 500; u += 512)
    ((float4*)hu4)[u] = *(const float4*)(hu + (size_t)b*2000 + u*4);

  // ---- stageb (x-gates from gx rows 2048+n) ----
  int s = tid / 100, j2 = tid - s*100;
  if (tid < 500){
    int n = b*5 + s;
    ((float*)stcat4)[s*200 + j2] = user[(size_t)sn2[n]*E_DIM + j2];
    const float* gr = gx + (size_t)(2048+n)*400;
    float c0  = fsig(gr[j2]) * ftanh(gr[200+j2]);
    ((float*)stcat4)[s*200 + 100 + j2] = fsig(gr[300+j2]) * ftanh(c0);
  }
  __syncthreads();
  if (tid < 500){
    float acc = 0.f;
    const float4* w1=(const float4*)(W1 + (size_t)j2*200);
#pragma unroll
    for (int k=0;k<50;k++) acc += dot4(w1[k], stcat4[s][k]);
    ls2l[s][j2] = fmaxf(acc, 0.f);
  }
  __syncthreads();

  // ---- GAT -> h04 ----
  if (tid < 100) ns[5][tid] = ((float*)hu4)[tid];
  if (tid < 500) ns[s][j2] = ls2l[s][j2];
  __syncthreads();
  if (tid < 6){ float sc=0.f; for (int e=0;e<100;e++) sc += ns[5][e]*ns[tid][e]; wsc[tid]=sc; }
  __syncthreads();
  if (tid == 0){
    float m=wsc[0]; for (int k=1;k<6;k++) m=fmaxf(m,wsc[k]);
    float sum=0.f;
    for (int k=0;k<6;k++){ float e_=expf(wsc[k]-m); wsc[k]=e_; sum+=e_; }
    float inv=1.f/sum;
    for (int k=0;k<6;k++) wsc[k]*=inv;
  }
  __syncthreads();
  if (tid < 100){ float cx=0.f; for (int k=0;k<6;k++) cx += wsc[k]*ns[k][tid]; ctx[tid]=cx; }
  __syncthreads();
  if (tid < 100){
    float acc=0.f;
    for (int e=0;e<100;e++) acc += ctx[e]*Wg0[e*E_DIM + tid];
    ((float*)h04)[tid] = fmaxf(acc, 0.f);
  }
  __syncthreads();

  // ---- sr rows (mask folded), bf16, K-pad ----
  {
    int mi4 = tid >> 7;
    int jj  = tid & 127;
#pragma unroll
    for (int r=0;r<5;r++){
      int mi = r*4 + mi4;
      int m  = b*L_SEQ + mi;
      unsigned short val = 0;
      if (jj < 100){
        float acc = 0.f;
        const float4* w2=(const float4*)(W2 + (size_t)jj*200);
#pragma unroll
        for (int k=0;k<25;k++) acc += dot4(w2[k],    hu4[mi][k]);
#pragma unroll
        for (int k=0;k<25;k++) acc += dot4(w2[25+k], h04[k]);
        acc *= (float)mask[m];
        val = f2bf(acc);
      }
      srb[(size_t)m*KP + jj] = val;
    }
    if (b < 48 && tid < 128) srb[(size_t)(MROWS + b)*KP + tid] = 0;
  }
}

// ---------------- E: logits = srb @ ib^T (bf16 MFMA, f32 acc) ----------------
__global__ __launch_bounds__(256) void gemm_kernel(
    const unsigned short* __restrict__ srb, const unsigned short* __restrict__ ib,
    float* __restrict__ out){
  __shared__ unsigned short As[128*KP];
  __shared__ unsigned short Bs[128*KP];
  int orig = blockIdx.x;               // 0..3759 = 8 XCD * 470
  int xcd  = orig & 7;
  int p    = orig >> 3;
  int tile_n = p >> 1;
  int tile_m = (xcd << 1) | (p & 1);
  int tid = threadIdx.x;
  const float4* Ag = (const float4*)(srb + (size_t)tile_m*128*KP);
  const float4* Bg = (const float4*)(ib  + (size_t)tile_n*128*KP);
  float4* As4=(float4*)As; float4* Bs4=(float4*)Bs;
#pragma unroll
  for (int i=0;i<8;i++){
    int chunk = i*256 + tid;
    int row = chunk >> 4;
    int cb  = (chunk & 15) << 4;
    int sw  = cb ^ ((row & 7) << 4);
    int di  = row*16 + (sw >> 4);
    As4[di] = Ag[chunk];
    Bs4[di] = Bg[chunk];
  }
  __syncthreads();
  int wave = tid >> 6, lane = tid & 63;
  int wm = (wave >> 1) << 6, wn = (wave & 1) << 6;
  int lrow = lane & 15, lq = lane >> 4;
  f32x4 acc[4][4];
#pragma unroll
  for (int i=0;i<4;i++)
#pragma unroll
    for (int jj=0;jj<4;jj++) acc[i][jj] = (f32x4){0.f,0.f,0.f,0.f};
#pragma unroll
  for (int kk=0;kk<4;kk++){
    int koffb = (kk*32 + lq*8) * 2;
    bf16x8 a[4], bfr[4];
#pragma unroll
    for (int i=0;i<4;i++){
      int row = wm + i*16 + lrow;
      int boff = koffb ^ ((row & 7) << 4);
      a[i] = *(const bf16x8*)(As + row*KP + (boff >> 1));
    }
#pragma unroll
    for (int jj=0;jj<4;jj++){
      int row = wn + jj*16 + lrow;
      int boff = koffb ^ ((row & 7) << 4);
      bfr[jj] = *(const bf16x8*)(Bs + row*KP + (boff >> 1));
    }
#pragma unroll
    for (int i=0;i<4;i++)
#pragma unroll
      for (int jj=0;jj<4;jj++)
        acc[i][jj] = __builtin_amdgcn_mfma_f32_16x16x32_bf16(bfr[jj], a[i], acc[i][jj], 0, 0, 0);
  }
  int v0 = tile_n*128 + wn + lq*4;
  int m0 = tile_m*128 + wm + lrow;
#pragma unroll
  for (int i=0;i<4;i++){
    int m = m0 + i*16;
    if (m < MROWS){
#pragma unroll
      for (int jj=0;jj<4;jj++){
        int v = v0 + jj*16;
        if (v < NV)
          *(float4*)(out + (size_t)m*NV + v) = (float4){acc[i][jj][0], acc[i][jj][1], acc[i][jj][2], acc[i][jj][3]};
      }
    }
  }
}

extern "C" void kernel_launch(void* const* d_in, const int* in_sizes, int n_in,
                              void* d_out, int out_size, void* d_ws, size_t ws_size,
                              hipStream_t stream) {
  const int*   seq  = (const int*)d_in[0];
  const int*   sn2  = (const int*)d_in[2];
  const int*   ss2  = (const int*)d_in[4];
  const int*   mask = (const int*)d_in[5];
  const float* user = (const float*)d_in[6];
  const float* item = (const float*)d_in[7];
  const float* W_ih = (const float*)d_in[8];
  const float* W_hh = (const float*)d_in[9];
  const float* b_ih = (const float*)d_in[10];
  const float* b_hh = (const float*)d_in[11];
  const float* W1   = (const float*)d_in[12];
  const float* W2   = (const float*)d_in[13];
  const float* Wg0  = (const float*)d_in[14];
  float* out = (float*)d_out;
  char* ws = (char*)d_ws;

  unsigned short* ib    = (unsigned short*)(ws);              // 7,700,480 B
  unsigned short* srb   = (unsigned short*)(ws + 7700480);    //   524,288 B
  unsigned short* xg    = (unsigned short*)(ws + 8224768);    //   655,360 B
  unsigned short* wihb  = (unsigned short*)(ws + 8880128);    //   131,072 B
  unsigned short* whhb  = (unsigned short*)(ws + 9011200);    //    89,600 B
  float*          biasv = (float*)(ws + 9100800);             //     2,048 B
  float*          gx    = (float*)(ws + 9102848);             // 4,096,000 B
  float*          hu    = (float*)(ws + 13198848);            //   800,000 B

  gather_kernel<<<dim3(4190), dim3(256), 0, stream>>>(
      seq, ss2, item, W_ih, W_hh, b_ih, b_hh, ib, xg, wihb, whhb, biasv);
  gxgemm_kernel<<<dim3(80), dim3(256), 0, stream>>>(xg, wihb, biasv, gx);
  rec_kernel<<<dim3(7), dim3(512), 0, stream>>>(whhb, gx, hu);
  rest_kernel<<<dim3(100), dim3(512), 0, stream>>>(
      sn2, mask, user, W1, W2, Wg0, gx, hu, srb);
  gemm_kernel<<<dim3(3760), dim3(256), 0, stream>>>(srb, ib, out);
}

// Round 9
// 119.092 us; speedup vs baseline: 1.2409x; 1.2409x over previous
//
#include <hip/hip_runtime.h>

typedef __attribute__((ext_vector_type(8))) short bf16x8;
typedef __attribute__((ext_vector_type(4))) float f32x4;
typedef __attribute__((ext_vector_type(4))) unsigned short us4;

#define E_DIM 100
#define L_SEQ 20
#define NV    30000
#define NVP   30080
#define MROWS 2000
#define KP    128
#define KW    112       // whh padded K

__device__ inline unsigned short f2bf(float f){
  unsigned int u = __float_as_uint(f);
  return (unsigned short)((u + 0x7fffu + ((u>>16)&1u)) >> 16);
}
__device__ inline float dot4(float4 a, float4 b){
  return a.x*b.x + a.y*b.y + a.z*b.z + a.w*b.w;
}
__device__ inline void store4bf(unsigned short* dst, float4 x){
  us4 p = { f2bf(x.x), f2bf(x.y), f2bf(x.z), f2bf(x.w) };
  *(us4*)dst = p;
}
__device__ inline float fsig(float x){
  float t = __builtin_amdgcn_exp2f(x * -1.44269504f);
  return __builtin_amdgcn_rcpf(1.f + t);
}
__device__ inline float ftanh(float x){
  float cx = fminf(fmaxf(x, -15.f), 15.f);
  float t = __builtin_amdgcn_exp2f(cx * 2.88539008f);
  return (t - 1.f) * __builtin_amdgcn_rcpf(t + 1.f);
}

// ---------------- G: build all bf16 operands (pure streaming) ----------------
#define C1     962560
#define C2    1044480
#define C3    1060864
#define C4    1072064
#define C5    1072576
__global__ void gather_kernel(const int* __restrict__ seq, const int* __restrict__ ss2,
    const float* __restrict__ item, const float* __restrict__ W_ih,
    const float* __restrict__ W_hh, const float* __restrict__ b_ih,
    const float* __restrict__ b_hh,
    unsigned short* __restrict__ ib, unsigned short* __restrict__ xg,
    unsigned short* __restrict__ wihb, unsigned short* __restrict__ whhb,
    float* __restrict__ biasv){
  int id = blockIdx.x*256 + threadIdx.x;
  if (id < C1){
    int v = id >> 5, k4 = (id & 31) << 2;
    float4 x = {0.f,0.f,0.f,0.f};
    if (v < NV && k4 < 100) x = *(const float4*)(item + (size_t)v*E_DIM + k4);
    store4bf(ib + (size_t)v*KP + k4, x);
  } else if (id < C2){
    int idx = id - C1;
    int m = idx >> 5, k4 = (idx & 31) << 2;
    int src = -1;
    if (m < MROWS) src = seq[m];
    else if (m >= 2048 && m < 2548) src = ss2[(m-2048)*L_SEQ];
    float4 x = {0.f,0.f,0.f,0.f};
    if (src >= 0 && k4 < 100) x = *(const float4*)(item + (size_t)src*E_DIM + k4);
    store4bf(xg + (size_t)m*KP + k4, x);
  } else if (id < C3){
    int idx = id - C2;
    int j = idx >> 5, k4 = (idx & 31) << 2;
    float4 x = {0.f,0.f,0.f,0.f};
    if (j < 400 && k4 < 100) x = *(const float4*)(W_ih + (size_t)j*E_DIM + k4);
    store4bf(wihb + (size_t)j*KP + k4, x);
  } else if (id < C4){
    int idx = id - C3;
    int j = idx / 28, k4 = (idx - j*28) << 2;
    float4 x = {0.f,0.f,0.f,0.f};
    if (k4 < 100) x = *(const float4*)(W_hh + (size_t)j*E_DIM + k4);
    store4bf(whhb + (size_t)j*KW + k4, x);
  } else if (id < C5){
    int n = id - C4;
    biasv[n] = (n < 400) ? (b_ih[n] + b_hh[n]) : 0.f;
  }
}

// ---------------- GX: gx[m][n] = xg[m] . wihb[n] + biasv[n] (MFMA) ----------------
__global__ __launch_bounds__(256) void gxgemm_kernel(
    const unsigned short* __restrict__ xg, const unsigned short* __restrict__ wihb,
    const float* __restrict__ biasv, float* __restrict__ gx){
  __shared__ unsigned short As[128*KP];
  __shared__ unsigned short Bs[128*KP];
  int tile_m = blockIdx.x >> 2;
  int tile_n = blockIdx.x & 3;
  int tid = threadIdx.x;
  const float4* Ag = (const float4*)(xg   + (size_t)tile_m*128*KP);
  const float4* Bg = (const float4*)(wihb + (size_t)tile_n*128*KP);
  float4* As4=(float4*)As; float4* Bs4=(float4*)Bs;
#pragma unroll
  for (int i=0;i<8;i++){
    int chunk = i*256 + tid;
    int row = chunk >> 4;
    int cb  = (chunk & 15) << 4;
    int sw  = cb ^ ((row & 7) << 4);
    int di  = row*16 + (sw >> 4);
    As4[di] = Ag[chunk];
    Bs4[di] = Bg[chunk];
  }
  __syncthreads();
  int wave = tid >> 6, lane = tid & 63;
  int wm = (wave >> 1) << 6, wn = (wave & 1) << 6;
  int lrow = lane & 15, lq = lane >> 4;
  f32x4 acc[4][4];
#pragma unroll
  for (int i=0;i<4;i++)
#pragma unroll
    for (int jj=0;jj<4;jj++) acc[i][jj] = (f32x4){0.f,0.f,0.f,0.f};
#pragma unroll
  for (int kk=0;kk<4;kk++){
    int koffb = (kk*32 + lq*8) * 2;
    bf16x8 a[4], bfr[4];
#pragma unroll
    for (int i=0;i<4;i++){
      int row = wm + i*16 + lrow;
      int boff = koffb ^ ((row & 7) << 4);
      a[i] = *(const bf16x8*)(As + row*KP + (boff >> 1));
    }
#pragma unroll
    for (int jj=0;jj<4;jj++){
      int row = wn + jj*16 + lrow;
      int boff = koffb ^ ((row & 7) << 4);
      bfr[jj] = *(const bf16x8*)(Bs + row*KP + (boff >> 1));
    }
#pragma unroll
    for (int i=0;i<4;i++)
#pragma unroll
      for (int jj=0;jj<4;jj++)
        acc[i][jj] = __builtin_amdgcn_mfma_f32_16x16x32_bf16(bfr[jj], a[i], acc[i][jj], 0, 0, 0);
  }
  int n0 = tile_n*128 + wn + lq*4;
  int m0 = tile_m*128 + wm + lrow;
#pragma unroll
  for (int i=0;i<4;i++){
    int m = m0 + i*16;
#pragma unroll
    for (int jj=0;jj<4;jj++){
      int n = n0 + jj*16;
      if (n < 400){
        float4 bv = *(const float4*)(biasv + n);
        *(float4*)(gx + (size_t)m*400 + n) =
          (float4){acc[i][jj][0]+bv.x, acc[i][jj][1]+bv.y, acc[i][jj][2]+bv.z, acc[i][jj][3]+bv.w};
      }
    }
  }
}

// ---------------- PREP: one block/session; MFMA recurrence in-place ----------------
// gates = W_hh(arg1, rows->C/D row axis) x h-replicated(arg2). Wave w owns
// n-tiles {w, w+8, w+16, w+24}; W-frags pinned (<=64 VGPR). h bf16 broadcast
// from LDS (same addr per 16-lane group -> conflict-free). gx staged to LDS.
__global__ __launch_bounds__(512,1) void prep_kernel(
    const int* __restrict__ sn2, const int* __restrict__ mask,
    const float* __restrict__ user, const float* __restrict__ W1,
    const float* __restrict__ W2, const float* __restrict__ Wg0,
    const unsigned short* __restrict__ whhb, const float* __restrict__ gx,
    unsigned short* __restrict__ srb){
  int b = blockIdx.x, tid = threadIdx.x;
  int wave = tid >> 6, lane = tid & 63;
  int lrow = lane & 15, lq = lane >> 4;
  __shared__ float  gxl[L_SEQ][400];     // 32,000 B  x-gates (incl bias)
  __shared__ unsigned short hsb[128];    // h bf16, k-padded
  __shared__ float  gsh[400];
  __shared__ float4 hu4[L_SEQ][25];
  __shared__ float4 stcat4[5][50];
  __shared__ float  ls2l[5][100];
  __shared__ float  ns[6][100];
  __shared__ float  wsc[8];
  __shared__ float  ctx[100];
  __shared__ float4 h04[25];

  // stage gx rows for this block (2000 float4, coalesced)
  {
    const float4* src = (const float4*)(gx + (size_t)b*L_SEQ*400);
    for (int u = tid; u < 2000; u += 512) ((float4*)gxl)[u] = src[u];
  }
  if (tid < 128) hsb[tid] = 0;

  // W_hh fragments: wave w tiles {w, w+8, w+16, w+24}; lane l -> row nt*16+(l&15),
  // k = ks*32 + (l>>4)*8 .. +8  (zero beyond KW=112)
  bf16x8 wf[4][4];
#pragma unroll
  for (int i=0;i<4;i++){
    int nt = wave + 8*i;
#pragma unroll
    for (int ks=0; ks<4; ks++){
      bf16x8 z = {0,0,0,0,0,0,0,0};
      int k = ks*32 + lq*8;
      if (nt < 25 && k < KW)
        z = *(const bf16x8*)(whhb + (size_t)(nt*16 + lrow)*KW + k);
      wf[i][ks] = z;
    }
  }
  float c = 0.f;
  __syncthreads();

  // ---- recurrence: 20 steps ----
  for (int tt=0; tt<L_SEQ; tt++){
    // h-replicated frags: broadcast read (same addr per lq group)
    bf16x8 hf[4];
#pragma unroll
    for (int ks=0; ks<4; ks++)
      hf[ks] = *(const bf16x8*)(hsb + ks*32 + lq*8);
#pragma unroll
    for (int i=0;i<4;i++){
      int nt = wave + 8*i;
      if (nt < 25){
        f32x4 acc = (f32x4){0.f,0.f,0.f,0.f};
#pragma unroll
        for (int ks=0; ks<4; ks++)
          acc = __builtin_amdgcn_mfma_f32_16x16x32_bf16(wf[i][ks], hf[ks], acc, 0, 0, 0);
        // D[r][c] = gates[nt*16 + r] for all c; lane holds rows lq*4..lq*4+3
        if (lrow == 0) *(f32x4*)(&gsh[nt*16 + lq*4]) = acc;
      }
    }
    __syncthreads();
    if (tid < 100){
      float g0 = gsh[tid      ] + gxl[tt][tid      ];
      float g1 = gsh[tid + 100] + gxl[tt][tid + 100];
      float g2 = gsh[tid + 200] + gxl[tt][tid + 200];
      float g3 = gsh[tid + 300] + gxl[tt][tid + 300];
      float ig = fsig(g0), fg = fsig(g1);
      float gg = ftanh(g2), og = fsig(g3);
      c = fg*c + ig*gg;
      float h = og * ftanh(c);
      hsb[tid] = f2bf(h);
      ((float*)hu4[tt])[tid] = h;
    }
    __syncthreads();
  }

  // ---- stageb (x-gates from gx rows 2048+n) ----
  int s = tid / 100, j2 = tid - s*100;
  if (tid < 500){
    int n = b*5 + s;
    ((float*)stcat4)[s*200 + j2] = user[(size_t)sn2[n]*E_DIM + j2];
    const float* gr = gx + (size_t)(2048+n)*400;
    float c0  = fsig(gr[j2]) * ftanh(gr[200+j2]);
    ((float*)stcat4)[s*200 + 100 + j2] = fsig(gr[300+j2]) * ftanh(c0);
  }
  __syncthreads();
  if (tid < 500){
    float acc = 0.f;
    const float4* w1=(const float4*)(W1 + (size_t)j2*200);
#pragma unroll
    for (int k=0;k<50;k++) acc += dot4(w1[k], stcat4[s][k]);
    ls2l[s][j2] = fmaxf(acc, 0.f);
  }
  __syncthreads();

  // ---- GAT -> h04 (scores wave-parallel) ----
  if (tid < 100) ns[5][tid] = ((float*)hu4[0])[tid];
  if (tid < 500) ns[s][j2] = ls2l[s][j2];
  __syncthreads();
  if (wave < 6){
    float p = 0.f;
    if (lane < 100) p = ns[5][lane] * ns[wave][lane];
    if (lane + 64 < 100) p += ns[5][lane+64] * ns[wave][lane+64];
#pragma unroll
    for (int off=32; off>0; off>>=1) p += __shfl_xor(p, off);
    if (lane == 0) wsc[wave] = p;
  }
  __syncthreads();
  if (tid == 0){
    float m=wsc[0]; for (int k=1;k<6;k++) m=fmaxf(m,wsc[k]);
    float sum=0.f;
    for (int k=0;k<6;k++){ float e_=__builtin_amdgcn_exp2f((wsc[k]-m)*1.44269504f); wsc[k]=e_; sum+=e_; }
    float inv=1.f/sum;
    for (int k=0;k<6;k++) wsc[k]*=inv;
  }
  __syncthreads();
  if (tid < 100){ float cx=0.f; for (int k=0;k<6;k++) cx += wsc[k]*ns[k][tid]; ctx[tid]=cx; }
  __syncthreads();
  if (tid < 100){
    float acc=0.f;
    for (int e=0;e<100;e++) acc += ctx[e]*Wg0[e*E_DIM + tid];
    ((float*)h04)[tid] = fmaxf(acc, 0.f);
  }
  __syncthreads();

  // ---- sr rows (mask folded), bf16, K-pad ----
  {
    int mi4 = tid >> 7;
    int jj  = tid & 127;
#pragma unroll
    for (int r=0;r<5;r++){
      int mi = r*4 + mi4;
      int m  = b*L_SEQ + mi;
      unsigned short val = 0;
      if (jj < 100){
        float acc = 0.f;
        const float4* w2=(const float4*)(W2 + (size_t)jj*200);
#pragma unroll
        for (int k=0;k<25;k++) acc += dot4(w2[k],    hu4[mi][k]);
#pragma unroll
        for (int k=0;k<25;k++) acc += dot4(w2[25+k], h04[k]);
        acc *= (float)mask[m];
        val = f2bf(acc);
      }
      srb[(size_t)m*KP + jj] = val;
    }
    if (b < 48 && tid < 128) srb[(size_t)(MROWS + b)*KP + tid] = 0;
  }
}

// ---------------- E: logits = srb @ ib^T (bf16 MFMA, f32 acc) ----------------
__global__ __launch_bounds__(256) void gemm_kernel(
    const unsigned short* __restrict__ srb, const unsigned short* __restrict__ ib,
    float* __restrict__ out){
  __shared__ unsigned short As[128*KP];
  __shared__ unsigned short Bs[128*KP];
  int orig = blockIdx.x;               // 0..3759 = 8 XCD * 470
  int xcd  = orig & 7;
  int p    = orig >> 3;
  int tile_n = p >> 1;
  int tile_m = (xcd << 1) | (p & 1);
  int tid = threadIdx.x;
  const float4* Ag = (const float4*)(srb + (size_t)tile_m*128*KP);
  const float4* Bg = (const float4*)(ib  + (size_t)tile_n*128*KP);
  float4* As4=(float4*)As; float4* Bs4=(float4*)Bs;
#pragma unroll
  for (int i=0;i<8;i++){
    int chunk = i*256 + tid;
    int row = chunk >> 4;
    int cb  = (chunk & 15) << 4;
    int sw  = cb ^ ((row & 7) << 4);
    int di  = row*16 + (sw >> 4);
    As4[di] = Ag[chunk];
    Bs4[di] = Bg[chunk];
  }
  __syncthreads();
  int wave = tid >> 6, lane = tid & 63;
  int wm = (wave >> 1) << 6, wn = (wave & 1) << 6;
  int lrow = lane & 15, lq = lane >> 4;
  f32x4 acc[4][4];
#pragma unroll
  for (int i=0;i<4;i++)
#pragma unroll
    for (int jj=0;jj<4;jj++) acc[i][jj] = (f32x4){0.f,0.f,0.f,0.f};
#pragma unroll
  for (int kk=0;kk<4;kk++){
    int koffb = (kk*32 + lq*8) * 2;
    bf16x8 a[4], bfr[4];
#pragma unroll
    for (int i=0;i<4;i++){
      int row = wm + i*16 + lrow;
      int boff = koffb ^ ((row & 7) << 4);
      a[i] = *(const bf16x8*)(As + row*KP + (boff >> 1));
    }
#pragma unroll
    for (int jj=0;jj<4;jj++){
      int row = wn + jj*16 + lrow;
      int boff = koffb ^ ((row & 7) << 4);
      bfr[jj] = *(const bf16x8*)(Bs + row*KP + (boff >> 1));
    }
#pragma unroll
    for (int i=0;i<4;i++)
#pragma unroll
      for (int jj=0;jj<4;jj++)
        acc[i][jj] = __builtin_amdgcn_mfma_f32_16x16x32_bf16(bfr[jj], a[i], acc[i][jj], 0, 0, 0);
  }
  int v0 = tile_n*128 + wn + lq*4;
  int m0 = tile_m*128 + wm + lrow;
#pragma unroll
  for (int i=0;i<4;i++){
    int m = m0 + i*16;
    if (m < MROWS){
#pragma unroll
      for (int jj=0;jj<4;jj++){
        int v = v0 + jj*16;
        if (v < NV)
          *(float4*)(out + (size_t)m*NV + v) = (float4){acc[i][jj][0], acc[i][jj][1], acc[i][jj][2], acc[i][jj][3]};
      }
    }
  }
}

extern "C" void kernel_launch(void* const* d_in, const int* in_sizes, int n_in,
                              void* d_out, int out_size, void* d_ws, size_t ws_size,
                              hipStream_t stream) {
  const int*   seq  = (const int*)d_in[0];
  const int*   sn2  = (const int*)d_in[2];
  const int*   ss2  = (const int*)d_in[4];
  const int*   mask = (const int*)d_in[5];
  const float* user = (const float*)d_in[6];
  const float* item = (const float*)d_in[7];
  const float* W_ih = (const float*)d_in[8];
  const float* W_hh = (const float*)d_in[9];
  const float* b_ih = (const float*)d_in[10];
  const float* b_hh = (const float*)d_in[11];
  const float* W1   = (const float*)d_in[12];
  const float* W2   = (const float*)d_in[13];
  const float* Wg0  = (const float*)d_in[14];
  float* out = (float*)d_out;
  char* ws = (char*)d_ws;

  unsigned short* ib    = (unsigned short*)(ws);              // 7,700,480 B
  unsigned short* srb   = (unsigned short*)(ws + 7700480);    //   524,288 B
  unsigned short* xg    = (unsigned short*)(ws + 8224768);    //   655,360 B
  unsigned short* wihb  = (unsigned short*)(ws + 8880128);    //   131,072 B
  unsigned short* whhb  = (unsigned short*)(ws + 9011200);    //    89,600 B
  float*          biasv = (float*)(ws + 9100800);             //     2,048 B
  float*          gx    = (float*)(ws + 9102848);             // 4,096,000 B

  gather_kernel<<<dim3(4190), dim3(256), 0, stream>>>(
      seq, ss2, item, W_ih, W_hh, b_ih, b_hh, ib, xg, wihb, whhb, biasv);
  gxgemm_kernel<<<dim3(80), dim3(256), 0, stream>>>(xg, wihb, biasv, gx);
  prep_kernel<<<dim3(100), dim3(512), 0, stream>>>(
      sn2, mask, user, W1, W2, Wg0, whhb, gx, srb);
  gemm_kernel<<<dim3(3760), dim3(256), 0, stream>>>(srb, ib, out);
}

// Round 10
// 101.107 us; speedup vs baseline: 1.4616x; 1.1779x over previous
//
#include <hip/hip_runtime.h>

typedef __attribute__((ext_vector_type(8))) short bf16x8;
typedef __attribute__((ext_vector_type(4))) float f32x4;
typedef __attribute__((ext_vector_type(4))) unsigned short us4;

#define E_DIM 100
#define L_SEQ 20
#define NV    30000
#define NVP   30080
#define MROWS 2000
#define KP    128
#define KW    112       // whh padded K
#define WSTR  53        // W1/W2 LDS row stride in float4 (gcd(53,8)=1 -> conflict-free b128)

__device__ inline unsigned short f2bf(float f){
  unsigned int u = __float_as_uint(f);
  return (unsigned short)((u + 0x7fffu + ((u>>16)&1u)) >> 16);
}
__device__ inline float dot4(float4 a, float4 b){
  return a.x*b.x + a.y*b.y + a.z*b.z + a.w*b.w;
}
__device__ inline void store4bf(unsigned short* dst, float4 x){
  us4 p = { f2bf(x.x), f2bf(x.y), f2bf(x.z), f2bf(x.w) };
  *(us4*)dst = p;
}
__device__ inline float fsig(float x){
  float t = __builtin_amdgcn_exp2f(x * -1.44269504f);
  return __builtin_amdgcn_rcpf(1.f + t);
}
__device__ inline float ftanh(float x){
  float cx = fminf(fmaxf(x, -15.f), 15.f);
  float t = __builtin_amdgcn_exp2f(cx * 2.88539008f);
  return (t - 1.f) * __builtin_amdgcn_rcpf(t + 1.f);
}

// ---------------- G: build all bf16 operands (pure streaming) ----------------
#define C1     962560
#define C2    1044480
#define C3    1060864
#define C4    1072064
#define C5    1072576
__global__ void gather_kernel(const int* __restrict__ seq, const int* __restrict__ ss2,
    const float* __restrict__ item, const float* __restrict__ W_ih,
    const float* __restrict__ W_hh, const float* __restrict__ b_ih,
    const float* __restrict__ b_hh,
    unsigned short* __restrict__ ib, unsigned short* __restrict__ xg,
    unsigned short* __restrict__ wihb, unsigned short* __restrict__ whhb,
    float* __restrict__ biasv){
  int id = blockIdx.x*256 + threadIdx.x;
  if (id < C1){
    int v = id >> 5, k4 = (id & 31) << 2;
    float4 x = {0.f,0.f,0.f,0.f};
    if (v < NV && k4 < 100) x = *(const float4*)(item + (size_t)v*E_DIM + k4);
    store4bf(ib + (size_t)v*KP + k4, x);
  } else if (id < C2){
    int idx = id - C1;
    int m = idx >> 5, k4 = (idx & 31) << 2;
    int src = -1;
    if (m < MROWS) src = seq[m];
    else if (m >= 2048 && m < 2548) src = ss2[(m-2048)*L_SEQ];
    float4 x = {0.f,0.f,0.f,0.f};
    if (src >= 0 && k4 < 100) x = *(const float4*)(item + (size_t)src*E_DIM + k4);
    store4bf(xg + (size_t)m*KP + k4, x);
  } else if (id < C3){
    int idx = id - C2;
    int j = idx >> 5, k4 = (idx & 31) << 2;
    float4 x = {0.f,0.f,0.f,0.f};
    if (j < 400 && k4 < 100) x = *(const float4*)(W_ih + (size_t)j*E_DIM + k4);
    store4bf(wihb + (size_t)j*KP + k4, x);
  } else if (id < C4){
    int idx = id - C3;
    int j = idx / 28, k4 = (idx - j*28) << 2;
    float4 x = {0.f,0.f,0.f,0.f};
    if (k4 < 100) x = *(const float4*)(W_hh + (size_t)j*E_DIM + k4);
    store4bf(whhb + (size_t)j*KW + k4, x);
  } else if (id < C5){
    int n = id - C4;
    biasv[n] = (n < 400) ? (b_ih[n] + b_hh[n]) : 0.f;
  }
}

// ---------------- GX: gx[m][n] = xg[m] . wihb[n] + biasv[n] (MFMA) ----------------
__global__ __launch_bounds__(256) void gxgemm_kernel(
    const unsigned short* __restrict__ xg, const unsigned short* __restrict__ wihb,
    const float* __restrict__ biasv, float* __restrict__ gx){
  __shared__ unsigned short As[128*KP];
  __shared__ unsigned short Bs[128*KP];
  int tile_m = blockIdx.x >> 2;
  int tile_n = blockIdx.x & 3;
  int tid = threadIdx.x;
  const float4* Ag = (const float4*)(xg   + (size_t)tile_m*128*KP);
  const float4* Bg = (const float4*)(wihb + (size_t)tile_n*128*KP);
  float4* As4=(float4*)As; float4* Bs4=(float4*)Bs;
#pragma unroll
  for (int i=0;i<8;i++){
    int chunk = i*256 + tid;
    int row = chunk >> 4;
    int cb  = (chunk & 15) << 4;
    int sw  = cb ^ ((row & 7) << 4);
    int di  = row*16 + (sw >> 4);
    As4[di] = Ag[chunk];
    Bs4[di] = Bg[chunk];
  }
  __syncthreads();
  int wave = tid >> 6, lane = tid & 63;
  int wm = (wave >> 1) << 6, wn = (wave & 1) << 6;
  int lrow = lane & 15, lq = lane >> 4;
  f32x4 acc[4][4];
#pragma unroll
  for (int i=0;i<4;i++)
#pragma unroll
    for (int jj=0;jj<4;jj++) acc[i][jj] = (f32x4){0.f,0.f,0.f,0.f};
#pragma unroll
  for (int kk=0;kk<4;kk++){
    int koffb = (kk*32 + lq*8) * 2;
    bf16x8 a[4], bfr[4];
#pragma unroll
    for (int i=0;i<4;i++){
      int row = wm + i*16 + lrow;
      int boff = koffb ^ ((row & 7) << 4);
      a[i] = *(const bf16x8*)(As + row*KP + (boff >> 1));
    }
#pragma unroll
    for (int jj=0;jj<4;jj++){
      int row = wn + jj*16 + lrow;
      int boff = koffb ^ ((row & 7) << 4);
      bfr[jj] = *(const bf16x8*)(Bs + row*KP + (boff >> 1));
    }
#pragma unroll
    for (int i=0;i<4;i++)
#pragma unroll
      for (int jj=0;jj<4;jj++)
        acc[i][jj] = __builtin_amdgcn_mfma_f32_16x16x32_bf16(bfr[jj], a[i], acc[i][jj], 0, 0, 0);
  }
  int n0 = tile_n*128 + wn + lq*4;
  int m0 = tile_m*128 + wm + lrow;
#pragma unroll
  for (int i=0;i<4;i++){
    int m = m0 + i*16;
#pragma unroll
    for (int jj=0;jj<4;jj++){
      int n = n0 + jj*16;
      if (n < 400){
        float4 bv = *(const float4*)(biasv + n);
        *(float4*)(gx + (size_t)m*400 + n) =
          (float4){acc[i][jj][0]+bv.x, acc[i][jj][1]+bv.y, acc[i][jj][2]+bv.z, acc[i][jj][3]+bv.w};
      }
    }
  }
}

// ---------------- PREP: one block/session; MFMA recurrence; W1/W2 LDS-staged ------
// stageb/sr previously read a DIFFERENT 800B weight row per lane (64 cache
// lines per wave-load, W1/W2 > L1) -> L1 thrash. Now: W1 staged to LDS f32
// (stride-53 float4 rows, conflict-free b128), buffer restaged with W2 for sr.
__global__ __launch_bounds__(512,1) void prep_kernel(
    const int* __restrict__ sn2, const int* __restrict__ mask,
    const float* __restrict__ user, const float* __restrict__ W1,
    const float* __restrict__ W2, const float* __restrict__ Wg0,
    const unsigned short* __restrict__ whhb, const float* __restrict__ gx,
    unsigned short* __restrict__ srb){
  int b = blockIdx.x, tid = threadIdx.x;
  int wave = tid >> 6, lane = tid & 63;
  int lrow = lane & 15, lq = lane >> 4;
  __shared__ float4 Wsh[100*WSTR];       // 84,800 B: W1, then W2 (restaged)
  __shared__ float  gxl[L_SEQ][400];     // 32,000 B
  __shared__ unsigned short hsb[128];
  __shared__ float  gsh[400];
  __shared__ float4 hu4[L_SEQ][25];
  __shared__ float4 stcat4[5][50];
  __shared__ float  ls2l[5][100];
  __shared__ float  ns[6][100];
  __shared__ float  wsc[8];
  __shared__ float  ctx[100];
  __shared__ float4 h04[25];

  // stage gx rows for this block (2000 float4, coalesced) + W1 -> LDS
  {
    const float4* src = (const float4*)(gx + (size_t)b*L_SEQ*400);
    for (int u = tid; u < 2000; u += 512) ((float4*)gxl)[u] = src[u];
    const float4* w1g = (const float4*)W1;           // 100 rows x 50 f4
    for (int u = tid; u < 5000; u += 512){
      int r = u / 50, cc = u - r*50;
      Wsh[r*WSTR + cc] = w1g[u];
    }
  }
  if (tid < 128) hsb[tid] = 0;

  // W_hh fragments: wave w tiles {w, w+8, w+16, w+24}
  bf16x8 wf[4][4];
#pragma unroll
  for (int i=0;i<4;i++){
    int nt = wave + 8*i;
#pragma unroll
    for (int ks=0; ks<4; ks++){
      bf16x8 z = {0,0,0,0,0,0,0,0};
      int k = ks*32 + lq*8;
      if (nt < 25 && k < KW)
        z = *(const bf16x8*)(whhb + (size_t)(nt*16 + lrow)*KW + k);
      wf[i][ks] = z;
    }
  }
  float c = 0.f;
  __syncthreads();

  // ---- recurrence: 20 steps ----
  for (int tt=0; tt<L_SEQ; tt++){
    bf16x8 hf[4];
#pragma unroll
    for (int ks=0; ks<4; ks++)
      hf[ks] = *(const bf16x8*)(hsb + ks*32 + lq*8);
#pragma unroll
    for (int i=0;i<4;i++){
      int nt = wave + 8*i;
      if (nt < 25){
        f32x4 acc = (f32x4){0.f,0.f,0.f,0.f};
#pragma unroll
        for (int ks=0; ks<4; ks++)
          acc = __builtin_amdgcn_mfma_f32_16x16x32_bf16(wf[i][ks], hf[ks], acc, 0, 0, 0);
        if (lrow == 0) *(f32x4*)(&gsh[nt*16 + lq*4]) = acc;
      }
    }
    __syncthreads();
    if (tid < 100){
      float g0 = gsh[tid      ] + gxl[tt][tid      ];
      float g1 = gsh[tid + 100] + gxl[tt][tid + 100];
      float g2 = gsh[tid + 200] + gxl[tt][tid + 200];
      float g3 = gsh[tid + 300] + gxl[tt][tid + 300];
      float ig = fsig(g0), fg = fsig(g1);
      float gg = ftanh(g2), og = fsig(g3);
      c = fg*c + ig*gg;
      float h = og * ftanh(c);
      hsb[tid] = f2bf(h);
      ((float*)hu4[tt])[tid] = h;
    }
    __syncthreads();
  }

  // ---- stageb (x-gates from gx rows 2048+n; W1 from LDS) ----
  int s = tid / 100, j2 = tid - s*100;
  if (tid < 500){
    int n = b*5 + s;
    ((float*)stcat4)[s*200 + j2] = user[(size_t)sn2[n]*E_DIM + j2];
    const float* gr = gx + (size_t)(2048+n)*400;
    float c0  = fsig(gr[j2]) * ftanh(gr[200+j2]);
    ((float*)stcat4)[s*200 + 100 + j2] = fsig(gr[300+j2]) * ftanh(c0);
  }
  __syncthreads();
  if (tid < 500){
    float acc = 0.f;
    const float4* w1row = Wsh + j2*WSTR;
#pragma unroll
    for (int k=0;k<50;k++) acc += dot4(w1row[k], stcat4[s][k]);
    ls2l[s][j2] = fmaxf(acc, 0.f);
  }
  __syncthreads();           // all W1 reads done

  // restage Wsh with W2 (latency hidden under GAT phases)
  {
    const float4* w2g = (const float4*)W2;           // 100 rows x 50 f4
    for (int u = tid; u < 5000; u += 512){
      int r = u / 50, cc = u - r*50;
      Wsh[r*WSTR + cc] = w2g[u];
    }
  }

  // ---- GAT -> h04 (scores wave-parallel) ----
  if (tid < 100) ns[5][tid] = ((float*)hu4[0])[tid];
  if (tid < 500) ns[s][j2] = ls2l[s][j2];
  __syncthreads();
  if (wave < 6){
    float p = 0.f;
    if (lane < 100) p = ns[5][lane] * ns[wave][lane];
    if (lane + 64 < 100) p += ns[5][lane+64] * ns[wave][lane+64];
#pragma unroll
    for (int off=32; off>0; off>>=1) p += __shfl_xor(p, off);
    if (lane == 0) wsc[wave] = p;
  }
  __syncthreads();
  if (tid == 0){
    float m=wsc[0]; for (int k=1;k<6;k++) m=fmaxf(m,wsc[k]);
    float sum=0.f;
    for (int k=0;k<6;k++){ float e_=__builtin_amdgcn_exp2f((wsc[k]-m)*1.44269504f); wsc[k]=e_; sum+=e_; }
    float inv=1.f/sum;
    for (int k=0;k<6;k++) wsc[k]*=inv;
  }
  __syncthreads();
  if (tid < 100){ float cx=0.f; for (int k=0;k<6;k++) cx += wsc[k]*ns[k][tid]; ctx[tid]=cx; }
  __syncthreads();
  if (tid < 100){
    float acc=0.f;
    for (int e=0;e<100;e++) acc += ctx[e]*Wg0[e*E_DIM + tid];
    ((float*)h04)[tid] = fmaxf(acc, 0.f);
  }
  __syncthreads();           // h04 ready AND W2 restage visible

  // ---- sr rows (mask folded; W2 from LDS), bf16, K-pad ----
  {
    int mi4 = tid >> 7;
    int jj  = tid & 127;
#pragma unroll
    for (int r=0;r<5;r++){
      int mi = r*4 + mi4;
      int m  = b*L_SEQ + mi;
      unsigned short val = 0;
      if (jj < 100){
        float acc = 0.f;
        const float4* w2row = Wsh + jj*WSTR;
#pragma unroll
        for (int k=0;k<25;k++) acc += dot4(w2row[k],    hu4[mi][k]);
#pragma unroll
        for (int k=0;k<25;k++) acc += dot4(w2row[25+k], h04[k]);
        acc *= (float)mask[m];
        val = f2bf(acc);
      }
      srb[(size_t)m*KP + jj] = val;
    }
    if (b < 48 && tid < 128) srb[(size_t)(MROWS + b)*KP + tid] = 0;
  }
}

// ---------------- E: logits = srb @ ib^T (bf16 MFMA, f32 acc) ----------------
__global__ __launch_bounds__(256) void gemm_kernel(
    const unsigned short* __restrict__ srb, const unsigned short* __restrict__ ib,
    float* __restrict__ out){
  __shared__ unsigned short As[128*KP];
  __shared__ unsigned short Bs[128*KP];
  int orig = blockIdx.x;               // 0..3759 = 8 XCD * 470
  int xcd  = orig & 7;
  int p    = orig >> 3;
  int tile_n = p >> 1;
  int tile_m = (xcd << 1) | (p & 1);
  int tid = threadIdx.x;
  const float4* Ag = (const float4*)(srb + (size_t)tile_m*128*KP);
  const float4* Bg = (const float4*)(ib  + (size_t)tile_n*128*KP);
  float4* As4=(float4*)As; float4* Bs4=(float4*)Bs;
#pragma unroll
  for (int i=0;i<8;i++){
    int chunk = i*256 + tid;
    int row = chunk >> 4;
    int cb  = (chunk & 15) << 4;
    int sw  = cb ^ ((row & 7) << 4);
    int di  = row*16 + (sw >> 4);
    As4[di] = Ag[chunk];
    Bs4[di] = Bg[chunk];
  }
  __syncthreads();
  int wave = tid >> 6, lane = tid & 63;
  int wm = (wave >> 1) << 6, wn = (wave & 1) << 6;
  int lrow = lane & 15, lq = lane >> 4;
  f32x4 acc[4][4];
#pragma unroll
  for (int i=0;i<4;i++)
#pragma unroll
    for (int jj=0;jj<4;jj++) acc[i][jj] = (f32x4){0.f,0.f,0.f,0.f};
#pragma unroll
  for (int kk=0;kk<4;kk++){
    int koffb = (kk*32 + lq*8) * 2;
    bf16x8 a[4], bfr[4];
#pragma unroll
    for (int i=0;i<4;i++){
      int row = wm + i*16 + lrow;
      int boff = koffb ^ ((row & 7) << 4);
      a[i] = *(const bf16x8*)(As + row*KP + (boff >> 1));
    }
#pragma unroll
    for (int jj=0;jj<4;jj++){
      int row = wn + jj*16 + lrow;
      int boff = koffb ^ ((row & 7) << 4);
      bfr[jj] = *(const bf16x8*)(Bs + row*KP + (boff >> 1));
    }
#pragma unroll
    for (int i=0;i<4;i++)
#pragma unroll
      for (int jj=0;jj<4;jj++)
        acc[i][jj] = __builtin_amdgcn_mfma_f32_16x16x32_bf16(bfr[jj], a[i], acc[i][jj], 0, 0, 0);
  }
  int v0 = tile_n*128 + wn + lq*4;
  int m0 = tile_m*128 + wm + lrow;
#pragma unroll
  for (int i=0;i<4;i++){
    int m = m0 + i*16;
    if (m < MROWS){
#pragma unroll
      for (int jj=0;jj<4;jj++){
        int v = v0 + jj*16;
        if (v < NV)
          *(float4*)(out + (size_t)m*NV + v) = (float4){acc[i][jj][0], acc[i][jj][1], acc[i][jj][2], acc[i][jj][3]};
      }
    }
  }
}

extern "C" void kernel_launch(void* const* d_in, const int* in_sizes, int n_in,
                              void* d_out, int out_size, void* d_ws, size_t ws_size,
                              hipStream_t stream) {
  const int*   seq  = (const int*)d_in[0];
  const int*   sn2  = (const int*)d_in[2];
  const int*   ss2  = (const int*)d_in[4];
  const int*   mask = (const int*)d_in[5];
  const float* user = (const float*)d_in[6];
  const float* item = (const float*)d_in[7];
  const float* W_ih = (const float*)d_in[8];
  const float* W_hh = (const float*)d_in[9];
  const float* b_ih = (const float*)d_in[10];
  const float* b_hh = (const float*)d_in[11];
  const float* W1   = (const float*)d_in[12];
  const float* W2   = (const float*)d_in[13];
  const float* Wg0  = (const float*)d_in[14];
  float* out = (float*)d_out;
  char* ws = (char*)d_ws;

  unsigned short* ib    = (unsigned short*)(ws);              // 7,700,480 B
  unsigned short* srb   = (unsigned short*)(ws + 7700480);    //   524,288 B
  unsigned short* xg    = (unsigned short*)(ws + 8224768);    //   655,360 B
  unsigned short* wihb  = (unsigned short*)(ws + 8880128);    //   131,072 B
  unsigned short* whhb  = (unsigned short*)(ws + 9011200);    //    89,600 B
  float*          biasv = (float*)(ws + 9100800);             //     2,048 B
  float*          gx    = (float*)(ws + 9102848);             // 4,096,000 B

  gather_kernel<<<dim3(4190), dim3(256), 0, stream>>>(
      seq, ss2, item, W_ih, W_hh, b_ih, b_hh, ib, xg, wihb, whhb, biasv);
  gxgemm_kernel<<<dim3(80), dim3(256), 0, stream>>>(xg, wihb, biasv, gx);
  prep_kernel<<<dim3(100), dim3(512), 0, stream>>>(
      sn2, mask, user, W1, W2, Wg0, whhb, gx, srb);
  gemm_kernel<<<dim3(3760), dim3(256), 0, stream>>>(srb, ib, out);
}